// Round 15
// baseline (79.794 us; speedup 1.0000x reference)
//
#include <hip/hip_runtime.h>
#include <hip/hip_bf16.h>

#define BATCH 8
#define NPT   2048
#define DIM   512
#define NTM   8             // 2048/256 M-tiles per batch
#define NTN   16            // 2048/128 N-tiles per batch
#define NTPB  72            // tiles with j >= 2i  (16+14+...+2)
#define NBLK  (NTPB * BATCH) // 576

typedef __attribute__((ext_vector_type(4))) float f32x4;

// ---------------- workspace layout ----------------
// xn (fp8)  : 8,388,608 B at 0
#define OFF_SQ       16777216
#define OFF_MSUM     16842752
#define OFF_PARTIALS 16842784   // 576 floats

// ---------------- kernel 1: normalize rows, emit fp8 e4m3 + per-row |x_q|^2 ----------------
__global__ __launch_bounds__(256) void normalize_kernel(const float* __restrict__ emb,
                                                        unsigned char* __restrict__ xn,
                                                        float* __restrict__ sq) {
    const int wave = threadIdx.x >> 6;
    const int lane = threadIdx.x & 63;
    const int row  = blockIdx.x * 4 + wave;

    const float4* src = (const float4*)(emb + (size_t)row * DIM);
    float4 v0 = src[lane * 2 + 0];
    float4 v1 = src[lane * 2 + 1];

    float ss = v0.x*v0.x + v0.y*v0.y + v0.z*v0.z + v0.w*v0.w
             + v1.x*v1.x + v1.y*v1.y + v1.z*v1.z + v1.w*v1.w;
#pragma unroll
    for (int o = 32; o; o >>= 1) ss += __shfl_xor(ss, o);

    const float inv = 1.0f / fmaxf(sqrtf(ss), 1e-12f);

    const float f0 = v0.x*inv, f1 = v0.y*inv, f2 = v0.z*inv, f3 = v0.w*inv;
    const float f4 = v1.x*inv, f5 = v1.y*inv, f6 = v1.z*inv, f7 = v1.w*inv;

    int lo = __builtin_amdgcn_cvt_pk_fp8_f32(f0, f1, 0, 0);
    lo     = __builtin_amdgcn_cvt_pk_fp8_f32(f2, f3, lo, 1);
    int hi = __builtin_amdgcn_cvt_pk_fp8_f32(f4, f5, 0, 0);
    hi     = __builtin_amdgcn_cvt_pk_fp8_f32(f6, f7, hi, 1);

    float s2 = 0.f;
    {
        float a;
        a = __builtin_amdgcn_cvt_f32_fp8(lo, 0); s2 += a * a;
        a = __builtin_amdgcn_cvt_f32_fp8(lo, 1); s2 += a * a;
        a = __builtin_amdgcn_cvt_f32_fp8(lo, 2); s2 += a * a;
        a = __builtin_amdgcn_cvt_f32_fp8(lo, 3); s2 += a * a;
        a = __builtin_amdgcn_cvt_f32_fp8(hi, 0); s2 += a * a;
        a = __builtin_amdgcn_cvt_f32_fp8(hi, 1); s2 += a * a;
        a = __builtin_amdgcn_cvt_f32_fp8(hi, 2); s2 += a * a;
        a = __builtin_amdgcn_cvt_f32_fp8(hi, 3); s2 += a * a;
    }

    uint2 pk; pk.x = (unsigned)lo; pk.y = (unsigned)hi;
    *(uint2*)(xn + (size_t)row * DIM + lane * 8) = pk;

#pragma unroll
    for (int o = 32; o; o >>= 1) s2 += __shfl_xor(s2, o);
    if (lane == 0) sq[row] = s2;
}

// ---------------- kernel 2: per-batch mask sums ----------------
__global__ __launch_bounds__(256) void masksum_kernel(const float* __restrict__ mask,
                                                      float* __restrict__ msum) {
    const int b = blockIdx.x;
    float s = 0.f;
    for (int i = threadIdx.x; i < NPT; i += 256) s += mask[b * NPT + i];
#pragma unroll
    for (int o = 32; o; o >>= 1) s += __shfl_xor(s, o);
    __shared__ float ws[4];
    if ((threadIdx.x & 63) == 0) ws[threadIdx.x >> 6] = s;
    __syncthreads();
    if (threadIdx.x == 0) msum[b] = ws[0] + ws[1] + ws[2] + ws[3];
}

// ---------------- kernel 3: fp8 Gram, 256x128 tiles, 8 waves x (64x64), BK=32 ----------------
// WORK-PER-PHASE round: round-12 schedule verbatim (best measured: 4-region
// rotation, counted VMW, 1 barrier/phase) but 2x MFMA per wave-phase
// (16 MFMA + 8 ds_read vs 8+6) and HALF the blocks (576). Per-element symmetry
// weight (rlg<clg ? 2 : rlg==clg ? 1 : 0) replaces tile-doubling — exact.
// Budget: acc[4][4]=64 AGPR + ~46 arch <= 128 (launch_bounds 512,4) -> 4 waves/SIMD;
// LDS 57 KB -> 2 blocks/CU; 64 blocks/XCD share one batch's 1 MB panels (no L2 thrash).
// Staging: waves 0-3 A (2 loads/thr/region), waves 4-7 B (1 load/thr/region).
// VMW per side: steady 4|2, p14 2|1, p15 0. fp8 swizzle as rounds 12-14 (verified):
// store chunk c_src = c_phys ^ ((row>>2)&1); read octet koff = (lhi ^ ((llo>>2)&2))*8.
__global__ __launch_bounds__(512, 4) void gram_loss_kernel(const unsigned char* __restrict__ xn,
                                                           const float* __restrict__ sq,
                                                           const float* __restrict__ coords,
                                                           const float* __restrict__ mask,
                                                           float* __restrict__ partials) {
    __shared__ __align__(16) unsigned char ldsA[4][8192];   // 32 KB (256 rows x 32 k)
    __shared__ __align__(16) unsigned char ldsB[4][4096];   // 16 KB (128 rows x 32 k)
    __shared__ float s_sqr[256], s_mr[256], s_cr[256][3];
    __shared__ float s_sqc[128], s_mc[128], s_cc[128][3];
    __shared__ float s_wsum[8];

    // XCD-chunked: 576 = 8 * 72; batch == XCD id
    const int bid = blockIdx.x;
    const int b   = bid & 7;
    int idx = bid >> 3;
    int ti = 0;
    while (idx >= NTN - 2 * ti) { idx -= NTN - 2 * ti; ti++; }
    const int tj = 2 * ti + idx;              // j >= 2i : tile intersects upper triangle

    const int t    = threadIdx.x;
    const int wave = t >> 6, lane = t & 63;
    const int wr = wave >> 1, wc = wave & 1;  // 4 x 2 wave grid: 64x64 tiles
    const int lhi = lane >> 4, llo = lane & 15;

    const size_t rowBaseA = (size_t)(b * NPT + ti * 256);
    const size_t rowBaseB = (size_t)(b * NPT + tj * 128);

    f32x4 acc[4][4];
#pragma unroll
    for (int i = 0; i < 4; i++)
#pragma unroll
        for (int j = 0; j < 4; j++) acc[i][j] = (f32x4){0.f, 0.f, 0.f, 0.f};

    // staging addressing: side = wave>>2. Entry e in [0,256): row = e>>1, chunk = e&1.
    // A side (waves 0-3): entries t and t+256. B side (waves 4-7): entry t-256.
    const int side = wave >> 2;
    const int e    = side ? (t - 256) : t;
    const int row_ = e >> 1;
    const int chx  = (e & 1) ^ ((row_ >> 2) & 1);
    const unsigned char* gp = xn + (side ? rowBaseB : rowBaseA) * DIM;
    const unsigned char* g0 = gp + (size_t)row_ * DIM + chx * 16;
    const unsigned char* g1 = gp + (size_t)(row_ + 128) * DIM + chx * 16;  // A side only
    const int d0 = e * 16;
    const int d1 = (e + 256) * 16;

#define STAGE_REGION(q_)                                                                        \
    {                                                                                           \
        if (side == 0) {                                                                        \
            unsigned char* base_ = &ldsA[(q_) & 3][0];                                          \
            __builtin_amdgcn_global_load_lds(                                                   \
                (const __attribute__((address_space(1))) void*)(g0 + (q_) * 32),                \
                (__attribute__((address_space(3))) void*)(base_ + d0), 16, 0, 0);               \
            __builtin_amdgcn_global_load_lds(                                                   \
                (const __attribute__((address_space(1))) void*)(g1 + (q_) * 32),                \
                (__attribute__((address_space(3))) void*)(base_ + d1), 16, 0, 0);               \
        } else {                                                                                \
            __builtin_amdgcn_global_load_lds(                                                   \
                (const __attribute__((address_space(1))) void*)(g0 + (q_) * 32),                \
                (__attribute__((address_space(3))) void*)(&ldsB[(q_) & 3][0] + d0), 16, 0, 0);  \
        }                                                                                       \
    }

#define VMW(n_) asm volatile("s_waitcnt vmcnt(" #n_ ")" ::: "memory")

    // prologue: regions 0,1,2 in flight
    STAGE_REGION(0);
    STAGE_REGION(1);
    STAGE_REGION(2);

    const int koff   = (lhi ^ ((llo >> 2) & 2)) * 8;
    const int rowAby = (wr * 64 + llo) * 32;   // + mi*512
    const int rowBby = (wc * 64 + llo) * 32;   // + ni*512

#pragma unroll 1
    for (int p = 0; p < 16; p++) {
        if (p < 14)      { if (side == 0) { VMW(4); } else { VMW(2); } }
        else if (p == 14){ if (side == 0) { VMW(2); } else { VMW(1); } }
        else             { VMW(0); }
        __builtin_amdgcn_s_barrier();

        const unsigned char* baA = &ldsA[p & 3][0];
        const unsigned char* baB = &ldsB[p & 3][0];
        long af[4], bfr[4];
#pragma unroll
        for (int mi = 0; mi < 4; mi++)
            af[mi] = *(const long*)(baA + rowAby + mi * 512 + koff);
#pragma unroll
        for (int ni = 0; ni < 4; ni++)
            bfr[ni] = *(const long*)(baB + rowBby + ni * 512 + koff);

        if (p < 13) STAGE_REGION(p + 3);

        __builtin_amdgcn_s_setprio(1);
#pragma unroll
        for (int mi = 0; mi < 4; mi++)
#pragma unroll
            for (int ni = 0; ni < 4; ni++)
                acc[mi][ni] = __builtin_amdgcn_mfma_f32_16x16x32_fp8_fp8(af[mi], bfr[ni],
                                                                         acc[mi][ni], 0, 0, 0);
        __builtin_amdgcn_s_setprio(0);
    }

#undef STAGE_REGION
#undef VMW

    // stage per-row/col metadata for the epilogue
    __syncthreads();
    if (t < 256) {
        const int gi = b * NPT + ti * 256 + t;
        s_sqr[t]   = sq[gi];
        s_mr[t]    = mask[gi];
        s_cr[t][0] = coords[(size_t)gi * 3 + 0];
        s_cr[t][1] = coords[(size_t)gi * 3 + 1];
        s_cr[t][2] = coords[(size_t)gi * 3 + 2];
    } else if (t < 384) {
        const int rr = t - 256;
        const int gi = b * NPT + tj * 128 + rr;
        s_sqc[rr]   = sq[gi];
        s_mc[rr]    = mask[gi];
        s_cc[rr][0] = coords[(size_t)gi * 3 + 0];
        s_cc[rr][1] = coords[(size_t)gi * 3 + 1];
        s_cc[rr][2] = coords[(size_t)gi * 3 + 2];
    }
    __syncthreads();

    // C/D layout: col = lane&15, row = (lane>>4)*4 + reg
    const int rb = ti * 256, cb = tj * 128;
    float lsum = 0.f;
#pragma unroll
    for (int mi = 0; mi < 4; mi++) {
#pragma unroll
        for (int j = 0; j < 4; j++) {
            const int rl  = wr * 64 + mi * 16 + lhi * 4 + j;
            const float sqr = s_sqr[rl];
            const float mr  = s_mr[rl];
            const float cx = s_cr[rl][0], cy = s_cr[rl][1], cz = s_cr[rl][2];
            const int rlg = rb + rl;
#pragma unroll
            for (int ni = 0; ni < 4; ni++) {
                const int cl  = wc * 64 + ni * 16 + llo;
                const int clg = cb + cl;
                const float g  = acc[mi][ni][j];
                float d2 = sqr + s_sqc[cl] - 2.f * g;
                d2 = fmaxf(d2, 0.f);
                const float de = sqrtf(d2);
                const float lo = fmaxf(de - 1.0f, 0.f);
                const float dx = cx - s_cc[cl][0];
                const float dy = cy - s_cc[cl][1];
                const float dz = cz - s_cc[cl][2];
                const float cd2 = dx*dx + dy*dy + dz*dz;
                // symmetry weight: strict-upper counts twice, diagonal once, lower zero
                const float wsym = (rlg < clg) ? 2.f : ((rlg == clg) ? 1.f : 0.f);
                const float wgt = (cd2 < 100.0f) ? mr * s_mc[cl] * wsym : 0.f;
                lsum += lo * wgt;
            }
        }
    }

#pragma unroll
    for (int o = 32; o; o >>= 1) lsum += __shfl_xor(lsum, o);
    if (lane == 0) s_wsum[wave] = lsum;
    __syncthreads();
    if (t == 0) {
        float bs = 0.f;
#pragma unroll
        for (int i = 0; i < 8; i++) bs += s_wsum[i];
        partials[bid] = bs;
    }
}

// ---------------- kernel 4: final deterministic reduce ----------------
__global__ __launch_bounds__(256) void finalize_kernel(const float* __restrict__ partials,
                                                       const float* __restrict__ msum,
                                                       float* __restrict__ out) {
    double s = 0.0;
    for (int i = threadIdx.x; i < NBLK; i += 256) s += (double)partials[i];
#pragma unroll
    for (int o = 32; o; o >>= 1) s += __shfl_xor(s, o);
    __shared__ double ws[4];
    if ((threadIdx.x & 63) == 0) ws[threadIdx.x >> 6] = s;
    __syncthreads();
    if (threadIdx.x == 0) {
        const double tot = ws[0] + ws[1] + ws[2] + ws[3];
        double valid = 0.0;
        for (int bb = 0; bb < BATCH; bb++) valid += (double)msum[bb] * (double)msum[bb];
        out[0] = (float)(tot / (valid + 1e-8));
    }
}

extern "C" void kernel_launch(void* const* d_in, const int* in_sizes, int n_in,
                              void* d_out, int out_size, void* d_ws, size_t ws_size,
                              hipStream_t stream) {
    const float* emb    = (const float*)d_in[0];
    const float* coords = (const float*)d_in[1];
    const float* mask   = (const float*)d_in[2];

    char* ws = (char*)d_ws;
    unsigned char* xn  = (unsigned char*)ws;
    float* sq          = (float*)(ws + OFF_SQ);
    float* msum        = (float*)(ws + OFF_MSUM);
    float* partials    = (float*)(ws + OFF_PARTIALS);
    float* out         = (float*)d_out;

    normalize_kernel<<<dim3(BATCH * NPT / 4), dim3(256), 0, stream>>>(emb, xn, sq);
    masksum_kernel<<<dim3(BATCH), dim3(256), 0, stream>>>(mask, msum);
    gram_loss_kernel<<<dim3(NBLK), dim3(512), 0, stream>>>(xn, sq, coords, mask, partials);
    finalize_kernel<<<dim3(1), dim3(256), 0, stream>>>(partials, msum, out);
}

// Round 16
// 69.111 us; speedup vs baseline: 1.1546x; 1.1546x over previous
//
#include <hip/hip_runtime.h>
#include <hip/hip_bf16.h>

#define BATCH 8
#define NPT   2048
#define DIM   512
#define NTILE 16            // 2048/128 tiles per dim
#define NTRI  136           // 16*17/2 symmetric tiles per batch
#define NBLK  (NTRI * BATCH) // 1088

typedef __attribute__((ext_vector_type(4))) float f32x4;

// ---------------- workspace layout ----------------
// xn (fp8)  : 8,388,608 B at 0
#define OFF_SQ       16777216
#define OFF_PARTIALS 16842784   // 1088 floats

// ---------------- kernel 1: normalize rows, emit fp8 e4m3 + per-row |x_q|^2 ----------------
__global__ __launch_bounds__(256) void normalize_kernel(const float* __restrict__ emb,
                                                        unsigned char* __restrict__ xn,
                                                        float* __restrict__ sq) {
    const int wave = threadIdx.x >> 6;
    const int lane = threadIdx.x & 63;
    const int row  = blockIdx.x * 4 + wave;

    const float4* src = (const float4*)(emb + (size_t)row * DIM);
    float4 v0 = src[lane * 2 + 0];
    float4 v1 = src[lane * 2 + 1];

    float ss = v0.x*v0.x + v0.y*v0.y + v0.z*v0.z + v0.w*v0.w
             + v1.x*v1.x + v1.y*v1.y + v1.z*v1.z + v1.w*v1.w;
#pragma unroll
    for (int o = 32; o; o >>= 1) ss += __shfl_xor(ss, o);

    const float inv = 1.0f / fmaxf(sqrtf(ss), 1e-12f);

    const float f0 = v0.x*inv, f1 = v0.y*inv, f2 = v0.z*inv, f3 = v0.w*inv;
    const float f4 = v1.x*inv, f5 = v1.y*inv, f6 = v1.z*inv, f7 = v1.w*inv;

    int lo = __builtin_amdgcn_cvt_pk_fp8_f32(f0, f1, 0, 0);
    lo     = __builtin_amdgcn_cvt_pk_fp8_f32(f2, f3, lo, 1);
    int hi = __builtin_amdgcn_cvt_pk_fp8_f32(f4, f5, 0, 0);
    hi     = __builtin_amdgcn_cvt_pk_fp8_f32(f6, f7, hi, 1);

    float s2 = 0.f;
    {
        float a;
        a = __builtin_amdgcn_cvt_f32_fp8(lo, 0); s2 += a * a;
        a = __builtin_amdgcn_cvt_f32_fp8(lo, 1); s2 += a * a;
        a = __builtin_amdgcn_cvt_f32_fp8(lo, 2); s2 += a * a;
        a = __builtin_amdgcn_cvt_f32_fp8(lo, 3); s2 += a * a;
        a = __builtin_amdgcn_cvt_f32_fp8(hi, 0); s2 += a * a;
        a = __builtin_amdgcn_cvt_f32_fp8(hi, 1); s2 += a * a;
        a = __builtin_amdgcn_cvt_f32_fp8(hi, 2); s2 += a * a;
        a = __builtin_amdgcn_cvt_f32_fp8(hi, 3); s2 += a * a;
    }

    uint2 pk; pk.x = (unsigned)lo; pk.y = (unsigned)hi;
    *(uint2*)(xn + (size_t)row * DIM + lane * 8) = pk;

#pragma unroll
    for (int o = 32; o; o >>= 1) s2 += __shfl_xor(s2, o);
    if (lane == 0) sq[row] = s2;
}

// ---------------- kernel 2: fp8 Gram, 128x128 tile, 8 waves x (64x32), BK=32 ----------------
// Best-measured structure (round 12; 11 structural variants bracket 290-365 TF,
// this is the optimum): 4-region rotation (4 KB/side/region), stage 3 ahead,
// counted VMW(2), 1 barrier/phase. Staging: 1 gload_lds/thread/region
// (waves 0-3 A, 4-7 B). Swizzle: stored 16-B chunk c holds source chunk
// c ^ ((row>>2)&1); read octet = lhi ^ ((llo>>2)&2) -> 2-way bank aliasing
// (free per m136). Write-after-read safe: STAGE(p+3) overwrites region (p-1)&3,
// consumed before phase p-1's reads completed (barrier-separated).
__global__ __launch_bounds__(512, 4) void gram_loss_kernel(const unsigned char* __restrict__ xn,
                                                           const float* __restrict__ sq,
                                                           const float* __restrict__ coords,
                                                           const float* __restrict__ mask,
                                                           float* __restrict__ partials) {
    __shared__ __align__(16) unsigned char ldsA[4][4096];   // 16 KB
    __shared__ __align__(16) unsigned char ldsB[4][4096];   // 16 KB
    __shared__ float s_sqr[128], s_sqc[128], s_mr[128], s_mc[128];
    __shared__ float s_cr[128][3], s_cc[128][3];
    __shared__ float s_wsum[8];

    // XCD-chunked: 1088 = 8 * 136; batch == XCD id -> ~1 MB panel set per XCD L2
    const int bid = blockIdx.x;
    const int b   = bid & 7;
    int r = bid >> 3;
    int tm = 0;
    while (r >= NTILE - tm) { r -= NTILE - tm; tm++; }
    const int tn = tm + r;

    const int t    = threadIdx.x;
    const int wave = t >> 6, lane = t & 63;
    const int wr = wave >> 2, wc = wave & 3;      // 2 x 4 wave grid: 64-row x 32-col tiles
    const int lhi = lane >> 4, llo = lane & 15;

    const size_t rowBaseA = (size_t)(b * NPT + tm * 128);
    const size_t rowBaseB = (size_t)(b * NPT + tn * 128);

    f32x4 acc[4][2];
#pragma unroll
    for (int i = 0; i < 4; i++)
#pragma unroll
        for (int j = 0; j < 2; j++) acc[i][j] = (f32x4){0.f, 0.f, 0.f, 0.f};

    // staging: region = 128 rows x 32 k fp8 = 4 KB/side = 256 lanes x 16 B.
    // thread t: side = t>=256; l = t&255; row = l>>1; chunk = l&1;
    // source chunk pre-swizzled: (l&1) ^ ((row>>2)&1) -> byte ((2*(l&1))^((l>>3)&2))*8.
    const int ls    = t & 255;
    const int side  = t >> 8;                 // 0 = A (waves 0-3), 1 = B (waves 4-7)
    const int srow  = ls >> 1;
    const int scolB = ((2 * (ls & 1)) ^ ((ls >> 3) & 2)) * 8;

    const unsigned char* gsrc = xn + ((side ? rowBaseB : rowBaseA) + (size_t)srow) * DIM + scolB;
    const int dstoff = ls * 16;

#define STAGE_REGION(q_)                                                                        \
    {                                                                                           \
        unsigned char* d_ = (side ? &ldsB[(q_) & 3][0] : &ldsA[(q_) & 3][0]) + dstoff;          \
        __builtin_amdgcn_global_load_lds(                                                       \
            (const __attribute__((address_space(1))) void*)(gsrc + (q_) * 32),                  \
            (__attribute__((address_space(3))) void*)d_, 16, 0, 0);                             \
    }

#define VMW(n_) asm volatile("s_waitcnt vmcnt(" #n_ ")" ::: "memory")

    // prologue: regions 0,1,2 in flight (1 load/thread each)
    STAGE_REGION(0);
    STAGE_REGION(1);
    STAGE_REGION(2);

    // read: byte = row*32 + (lhi ^ ((llo>>2)&2))*8
    const int koff   = (lhi ^ ((llo >> 2) & 2)) * 8;
    const int rowAby = (wr * 64 + llo) * 32;   // + mi*512
    const int rowBby = (wc * 32 + llo) * 32;   // + ni*512

#pragma unroll 1
    for (int p = 0; p < 16; p++) {
        if (p < 14)      { VMW(2); }
        else if (p == 14){ VMW(1); }
        else             { VMW(0); }
        __builtin_amdgcn_s_barrier();

        const unsigned char* baA = &ldsA[p & 3][0];
        const unsigned char* baB = &ldsB[p & 3][0];
        long af[4], bfr[2];
#pragma unroll
        for (int mi = 0; mi < 4; mi++)
            af[mi] = *(const long*)(baA + rowAby + mi * 512 + koff);
#pragma unroll
        for (int ni = 0; ni < 2; ni++)
            bfr[ni] = *(const long*)(baB + rowBby + ni * 512 + koff);

        if (p < 13) STAGE_REGION(p + 3);

        __builtin_amdgcn_s_setprio(1);
#pragma unroll
        for (int mi = 0; mi < 4; mi++)
#pragma unroll
            for (int ni = 0; ni < 2; ni++)
                acc[mi][ni] = __builtin_amdgcn_mfma_f32_16x16x32_fp8_fp8(af[mi], bfr[ni],
                                                                         acc[mi][ni], 0, 0, 0);
        __builtin_amdgcn_s_setprio(0);
    }

#undef STAGE_REGION
#undef VMW

    // stage per-row/col metadata for the epilogue
    __syncthreads();
    if (t < 128) {
        const int gi = b * NPT + tm * 128 + t;
        s_sqr[t]   = sq[gi];
        s_mr[t]    = mask[gi];
        s_cr[t][0] = coords[(size_t)gi * 3 + 0];
        s_cr[t][1] = coords[(size_t)gi * 3 + 1];
        s_cr[t][2] = coords[(size_t)gi * 3 + 2];
    } else if (t < 256) {
        const int rr = t - 128;
        const int gi = b * NPT + tn * 128 + rr;
        s_sqc[rr]   = sq[gi];
        s_mc[rr]    = mask[gi];
        s_cc[rr][0] = coords[(size_t)gi * 3 + 0];
        s_cc[rr][1] = coords[(size_t)gi * 3 + 1];
        s_cc[rr][2] = coords[(size_t)gi * 3 + 2];
    }
    __syncthreads();

    // C/D layout: col = lane&15, row = (lane>>4)*4 + reg
    float lsum = 0.f;
#pragma unroll
    for (int mi = 0; mi < 4; mi++) {
#pragma unroll
        for (int j = 0; j < 4; j++) {
            const int rl  = wr * 64 + mi * 16 + lhi * 4 + j;
            const float sqr = s_sqr[rl];
            const float mr  = s_mr[rl];
            const float cx = s_cr[rl][0], cy = s_cr[rl][1], cz = s_cr[rl][2];
#pragma unroll
            for (int ni = 0; ni < 2; ni++) {
                const int cl = wc * 32 + ni * 16 + llo;
                const float g  = acc[mi][ni][j];
                float d2 = sqr + s_sqc[cl] - 2.f * g;
                d2 = fmaxf(d2, 0.f);
                const float de = sqrtf(d2);
                const float lo = fmaxf(de - 1.0f, 0.f);
                const float dx = cx - s_cc[cl][0];
                const float dy = cy - s_cc[cl][1];
                const float dz = cz - s_cc[cl][2];
                const float cd2 = dx*dx + dy*dy + dz*dz;
                const float wgt = (cd2 < 100.0f) ? mr * s_mc[cl] : 0.f;
                lsum += lo * wgt;
            }
        }
    }
    // off-diagonal tiles stand for both (tm,tn) and (tn,tm)
    if (tm != tn) lsum *= 2.0f;

#pragma unroll
    for (int o = 32; o; o >>= 1) lsum += __shfl_xor(lsum, o);
    if (lane == 0) s_wsum[wave] = lsum;
    __syncthreads();
    if (t == 0) {
        float bs = 0.f;
#pragma unroll
        for (int i = 0; i < 8; i++) bs += s_wsum[i];
        partials[bid] = bs;
    }
}

// ---------------- kernel 3: final deterministic reduce (+ fused mask sums) ----------------
// masksum folded in: per batch, 2048 mask values reduced thread-strided + shuffle
// (deterministic fixed order). Removes one kernel launch vs rounds 10-15.
__global__ __launch_bounds__(256) void finalize_kernel(const float* __restrict__ partials,
                                                       const float* __restrict__ mask,
                                                       float* __restrict__ out) {
    __shared__ double ws[4];
    __shared__ float  msh[BATCH];

    // per-batch mask sums
    for (int bb = 0; bb < BATCH; bb++) {
        float s = 0.f;
        for (int i = threadIdx.x; i < NPT; i += 256) s += mask[bb * NPT + i];
#pragma unroll
        for (int o = 32; o; o >>= 1) s += __shfl_xor(s, o);
        __shared__ float w4[4];
        if ((threadIdx.x & 63) == 0) w4[threadIdx.x >> 6] = s;
        __syncthreads();
        if (threadIdx.x == 0) msh[bb] = w4[0] + w4[1] + w4[2] + w4[3];
        __syncthreads();
    }

    double s = 0.0;
    for (int i = threadIdx.x; i < NBLK; i += 256) s += (double)partials[i];
#pragma unroll
    for (int o = 32; o; o >>= 1) s += __shfl_xor(s, o);
    if ((threadIdx.x & 63) == 0) ws[threadIdx.x >> 6] = s;
    __syncthreads();
    if (threadIdx.x == 0) {
        const double tot = ws[0] + ws[1] + ws[2] + ws[3];
        double valid = 0.0;
        for (int bb = 0; bb < BATCH; bb++) valid += (double)msh[bb] * (double)msh[bb];
        out[0] = (float)(tot / (valid + 1e-8));
    }
}

extern "C" void kernel_launch(void* const* d_in, const int* in_sizes, int n_in,
                              void* d_out, int out_size, void* d_ws, size_t ws_size,
                              hipStream_t stream) {
    const float* emb    = (const float*)d_in[0];
    const float* coords = (const float*)d_in[1];
    const float* mask   = (const float*)d_in[2];

    char* ws = (char*)d_ws;
    unsigned char* xn  = (unsigned char*)ws;
    float* sq          = (float*)(ws + OFF_SQ);
    float* partials    = (float*)(ws + OFF_PARTIALS);
    float* out         = (float*)d_out;

    normalize_kernel<<<dim3(BATCH * NPT / 4), dim3(256), 0, stream>>>(emb, xn, sq);
    gram_loss_kernel<<<dim3(NBLK), dim3(512), 0, stream>>>(xn, sq, coords, mask, partials);
    finalize_kernel<<<dim3(1), dim3(256), 0, stream>>>(partials, mask, out);
}

// Round 17
// 56.044 us; speedup vs baseline: 1.4238x; 1.2332x over previous
//
#include <hip/hip_runtime.h>
#include <hip/hip_bf16.h>

#define BATCH 8
#define NPT   2048
#define DIM   512
#define NTILE 16            // 2048/128 tiles per dim
#define NTRI  136           // 16*17/2 symmetric tiles per batch
#define NBLK  (NTRI * BATCH) // 1088

typedef __attribute__((ext_vector_type(4))) float f32x4;

// ---------------- workspace layout ----------------
// xn (fp8)  : 8,388,608 B at 0
#define OFF_SQ       16777216
#define OFF_MSUM     16842752
#define OFF_PARTIALS 16842784   // 1088 floats

// ---------------- kernel 1: normalize rows, emit fp8 e4m3 + per-row |x_q|^2 ----------------
__global__ __launch_bounds__(256) void normalize_kernel(const float* __restrict__ emb,
                                                        unsigned char* __restrict__ xn,
                                                        float* __restrict__ sq) {
    const int wave = threadIdx.x >> 6;
    const int lane = threadIdx.x & 63;
    const int row  = blockIdx.x * 4 + wave;

    const float4* src = (const float4*)(emb + (size_t)row * DIM);
    float4 v0 = src[lane * 2 + 0];
    float4 v1 = src[lane * 2 + 1];

    float ss = v0.x*v0.x + v0.y*v0.y + v0.z*v0.z + v0.w*v0.w
             + v1.x*v1.x + v1.y*v1.y + v1.z*v1.z + v1.w*v1.w;
#pragma unroll
    for (int o = 32; o; o >>= 1) ss += __shfl_xor(ss, o);

    const float inv = 1.0f / fmaxf(sqrtf(ss), 1e-12f);

    const float f0 = v0.x*inv, f1 = v0.y*inv, f2 = v0.z*inv, f3 = v0.w*inv;
    const float f4 = v1.x*inv, f5 = v1.y*inv, f6 = v1.z*inv, f7 = v1.w*inv;

    int lo = __builtin_amdgcn_cvt_pk_fp8_f32(f0, f1, 0, 0);
    lo     = __builtin_amdgcn_cvt_pk_fp8_f32(f2, f3, lo, 1);
    int hi = __builtin_amdgcn_cvt_pk_fp8_f32(f4, f5, 0, 0);
    hi     = __builtin_amdgcn_cvt_pk_fp8_f32(f6, f7, hi, 1);

    float s2 = 0.f;
    {
        float a;
        a = __builtin_amdgcn_cvt_f32_fp8(lo, 0); s2 += a * a;
        a = __builtin_amdgcn_cvt_f32_fp8(lo, 1); s2 += a * a;
        a = __builtin_amdgcn_cvt_f32_fp8(lo, 2); s2 += a * a;
        a = __builtin_amdgcn_cvt_f32_fp8(lo, 3); s2 += a * a;
        a = __builtin_amdgcn_cvt_f32_fp8(hi, 0); s2 += a * a;
        a = __builtin_amdgcn_cvt_f32_fp8(hi, 1); s2 += a * a;
        a = __builtin_amdgcn_cvt_f32_fp8(hi, 2); s2 += a * a;
        a = __builtin_amdgcn_cvt_f32_fp8(hi, 3); s2 += a * a;
    }

    uint2 pk; pk.x = (unsigned)lo; pk.y = (unsigned)hi;
    *(uint2*)(xn + (size_t)row * DIM + lane * 8) = pk;

#pragma unroll
    for (int o = 32; o; o >>= 1) s2 += __shfl_xor(s2, o);
    if (lane == 0) sq[row] = s2;
}

// ---------------- kernel 2: per-batch mask sums (8 parallel blocks) ----------------
// NOTE round 16: fusing this into finalize (serial 8-batch loop in one block)
// cost 13 us. Keep it as an 8-block parallel kernel.
__global__ __launch_bounds__(256) void masksum_kernel(const float* __restrict__ mask,
                                                      float* __restrict__ msum) {
    const int b = blockIdx.x;
    float s = 0.f;
    for (int i = threadIdx.x; i < NPT; i += 256) s += mask[b * NPT + i];
#pragma unroll
    for (int o = 32; o; o >>= 1) s += __shfl_xor(s, o);
    __shared__ float ws[4];
    if ((threadIdx.x & 63) == 0) ws[threadIdx.x >> 6] = s;
    __syncthreads();
    if (threadIdx.x == 0) msum[b] = ws[0] + ws[1] + ws[2] + ws[3];
}

// ---------------- kernel 3: fp8 Gram, 128x128 tile, 8 waves x (64x32), BK=32 ----------------
// Best-measured structure across 16 rounds (round 12, 56.2 us total): 4-region
// rotation (4 KB/side/region), stage 3 ahead, counted VMW(2), 1 barrier/phase.
// Staging: 1 gload_lds/thread/region (waves 0-3 A, 4-7 B). Swizzle: stored 16-B
// chunk c holds source chunk c ^ ((row>>2)&1); read octet = lhi ^ ((llo>>2)&2)
// -> 2-way bank aliasing (free per m136). Write-after-read safe: STAGE(p+3)
// overwrites region (p-1)&3, whose reads completed behind phase p-1's barrier.
__global__ __launch_bounds__(512, 4) void gram_loss_kernel(const unsigned char* __restrict__ xn,
                                                           const float* __restrict__ sq,
                                                           const float* __restrict__ coords,
                                                           const float* __restrict__ mask,
                                                           float* __restrict__ partials) {
    __shared__ __align__(16) unsigned char ldsA[4][4096];   // 16 KB
    __shared__ __align__(16) unsigned char ldsB[4][4096];   // 16 KB
    __shared__ float s_sqr[128], s_sqc[128], s_mr[128], s_mc[128];
    __shared__ float s_cr[128][3], s_cc[128][3];
    __shared__ float s_wsum[8];

    // XCD-chunked: 1088 = 8 * 136; batch == XCD id -> ~1 MB panel set per XCD L2
    const int bid = blockIdx.x;
    const int b   = bid & 7;
    int r = bid >> 3;
    int tm = 0;
    while (r >= NTILE - tm) { r -= NTILE - tm; tm++; }
    const int tn = tm + r;

    const int t    = threadIdx.x;
    const int wave = t >> 6, lane = t & 63;
    const int wr = wave >> 2, wc = wave & 3;      // 2 x 4 wave grid: 64-row x 32-col tiles
    const int lhi = lane >> 4, llo = lane & 15;

    const size_t rowBaseA = (size_t)(b * NPT + tm * 128);
    const size_t rowBaseB = (size_t)(b * NPT + tn * 128);

    f32x4 acc[4][2];
#pragma unroll
    for (int i = 0; i < 4; i++)
#pragma unroll
        for (int j = 0; j < 2; j++) acc[i][j] = (f32x4){0.f, 0.f, 0.f, 0.f};

    // staging: region = 128 rows x 32 k fp8 = 4 KB/side = 256 lanes x 16 B.
    // thread t: side = t>=256; l = t&255; row = l>>1; chunk = l&1;
    // source chunk pre-swizzled: (l&1) ^ ((row>>2)&1) -> byte ((2*(l&1))^((l>>3)&2))*8.
    const int ls    = t & 255;
    const int side  = t >> 8;                 // 0 = A (waves 0-3), 1 = B (waves 4-7)
    const int srow  = ls >> 1;
    const int scolB = ((2 * (ls & 1)) ^ ((ls >> 3) & 2)) * 8;

    const unsigned char* gsrc = xn + ((side ? rowBaseB : rowBaseA) + (size_t)srow) * DIM + scolB;
    const int dstoff = ls * 16;

#define STAGE_REGION(q_)                                                                        \
    {                                                                                           \
        unsigned char* d_ = (side ? &ldsB[(q_) & 3][0] : &ldsA[(q_) & 3][0]) + dstoff;          \
        __builtin_amdgcn_global_load_lds(                                                       \
            (const __attribute__((address_space(1))) void*)(gsrc + (q_) * 32),                  \
            (__attribute__((address_space(3))) void*)d_, 16, 0, 0);                             \
    }

#define VMW(n_) asm volatile("s_waitcnt vmcnt(" #n_ ")" ::: "memory")

    // prologue: regions 0,1,2 in flight (1 load/thread each)
    STAGE_REGION(0);
    STAGE_REGION(1);
    STAGE_REGION(2);

    // read: byte = row*32 + (lhi ^ ((llo>>2)&2))*8
    const int koff   = (lhi ^ ((llo >> 2) & 2)) * 8;
    const int rowAby = (wr * 64 + llo) * 32;   // + mi*512
    const int rowBby = (wc * 32 + llo) * 32;   // + ni*512

#pragma unroll 1
    for (int p = 0; p < 16; p++) {
        if (p < 14)      { VMW(2); }
        else if (p == 14){ VMW(1); }
        else             { VMW(0); }
        __builtin_amdgcn_s_barrier();

        const unsigned char* baA = &ldsA[p & 3][0];
        const unsigned char* baB = &ldsB[p & 3][0];
        long af[4], bfr[2];
#pragma unroll
        for (int mi = 0; mi < 4; mi++)
            af[mi] = *(const long*)(baA + rowAby + mi * 512 + koff);
#pragma unroll
        for (int ni = 0; ni < 2; ni++)
            bfr[ni] = *(const long*)(baB + rowBby + ni * 512 + koff);

        if (p < 13) STAGE_REGION(p + 3);

        __builtin_amdgcn_s_setprio(1);
#pragma unroll
        for (int mi = 0; mi < 4; mi++)
#pragma unroll
            for (int ni = 0; ni < 2; ni++)
                acc[mi][ni] = __builtin_amdgcn_mfma_f32_16x16x32_fp8_fp8(af[mi], bfr[ni],
                                                                         acc[mi][ni], 0, 0, 0);
        __builtin_amdgcn_s_setprio(0);
    }

#undef STAGE_REGION
#undef VMW

    // stage per-row/col metadata for the epilogue
    __syncthreads();
    if (t < 128) {
        const int gi = b * NPT + tm * 128 + t;
        s_sqr[t]   = sq[gi];
        s_mr[t]    = mask[gi];
        s_cr[t][0] = coords[(size_t)gi * 3 + 0];
        s_cr[t][1] = coords[(size_t)gi * 3 + 1];
        s_cr[t][2] = coords[(size_t)gi * 3 + 2];
    } else if (t < 256) {
        const int rr = t - 128;
        const int gi = b * NPT + tn * 128 + rr;
        s_sqc[rr]   = sq[gi];
        s_mc[rr]    = mask[gi];
        s_cc[rr][0] = coords[(size_t)gi * 3 + 0];
        s_cc[rr][1] = coords[(size_t)gi * 3 + 1];
        s_cc[rr][2] = coords[(size_t)gi * 3 + 2];
    }
    __syncthreads();

    // C/D layout: col = lane&15, row = (lane>>4)*4 + reg
    float lsum = 0.f;
#pragma unroll
    for (int mi = 0; mi < 4; mi++) {
#pragma unroll
        for (int j = 0; j < 4; j++) {
            const int rl  = wr * 64 + mi * 16 + lhi * 4 + j;
            const float sqr = s_sqr[rl];
            const float mr  = s_mr[rl];
            const float cx = s_cr[rl][0], cy = s_cr[rl][1], cz = s_cr[rl][2];
#pragma unroll
            for (int ni = 0; ni < 2; ni++) {
                const int cl = wc * 32 + ni * 16 + llo;
                const float g  = acc[mi][ni][j];
                float d2 = sqr + s_sqc[cl] - 2.f * g;
                d2 = fmaxf(d2, 0.f);
                const float de = sqrtf(d2);
                const float lo = fmaxf(de - 1.0f, 0.f);
                const float dx = cx - s_cc[cl][0];
                const float dy = cy - s_cc[cl][1];
                const float dz = cz - s_cc[cl][2];
                const float cd2 = dx*dx + dy*dy + dz*dz;
                const float wgt = (cd2 < 100.0f) ? mr * s_mc[cl] : 0.f;
                lsum += lo * wgt;
            }
        }
    }
    // off-diagonal tiles stand for both (tm,tn) and (tn,tm)
    if (tm != tn) lsum *= 2.0f;

#pragma unroll
    for (int o = 32; o; o >>= 1) lsum += __shfl_xor(lsum, o);
    if (lane == 0) s_wsum[wave] = lsum;
    __syncthreads();
    if (t == 0) {
        float bs = 0.f;
#pragma unroll
        for (int i = 0; i < 8; i++) bs += s_wsum[i];
        partials[bid] = bs;
    }
}

// ---------------- kernel 4: final deterministic reduce ----------------
__global__ __launch_bounds__(256) void finalize_kernel(const float* __restrict__ partials,
                                                       const float* __restrict__ msum,
                                                       float* __restrict__ out) {
    double s = 0.0;
    for (int i = threadIdx.x; i < NBLK; i += 256) s += (double)partials[i];
#pragma unroll
    for (int o = 32; o; o >>= 1) s += __shfl_xor(s, o);
    __shared__ double ws[4];
    if ((threadIdx.x & 63) == 0) ws[threadIdx.x >> 6] = s;
    __syncthreads();
    if (threadIdx.x == 0) {
        const double tot = ws[0] + ws[1] + ws[2] + ws[3];
        double valid = 0.0;
        for (int bb = 0; bb < BATCH; bb++) valid += (double)msum[bb] * (double)msum[bb];
        out[0] = (float)(tot / (valid + 1e-8));
    }
}

extern "C" void kernel_launch(void* const* d_in, const int* in_sizes, int n_in,
                              void* d_out, int out_size, void* d_ws, size_t ws_size,
                              hipStream_t stream) {
    const float* emb    = (const float*)d_in[0];
    const float* coords = (const float*)d_in[1];
    const float* mask   = (const float*)d_in[2];

    char* ws = (char*)d_ws;
    unsigned char* xn  = (unsigned char*)ws;
    float* sq          = (float*)(ws + OFF_SQ);
    float* msum        = (float*)(ws + OFF_MSUM);
    float* partials    = (float*)(ws + OFF_PARTIALS);
    float* out         = (float*)d_out;

    normalize_kernel<<<dim3(BATCH * NPT / 4), dim3(256), 0, stream>>>(emb, xn, sq);
    masksum_kernel<<<dim3(BATCH), dim3(256), 0, stream>>>(mask, msum);
    gram_loss_kernel<<<dim3(NBLK), dim3(512), 0, stream>>>(xn, sq, coords, mask, partials);
    finalize_kernel<<<dim3(1), dim3(256), 0, stream>>>(partials, msum, out);
}